// Round 3
// baseline (1061.671 us; speedup 1.0000x reference)
//
#include <hip/hip_runtime.h>

#define LTOT 2112
#define NROWS 8448   // 4 * 2112
#define DM 512
#define DIN 1024
#define NST 256

using short8 = short  __attribute__((ext_vector_type(8)));
using f32x4  = float  __attribute__((ext_vector_type(4)));

__device__ __forceinline__ float fast_silu(float x){ return x / (1.f + __expf(-x)); }

__device__ __forceinline__ unsigned short f2bf(float f){
  unsigned u = __float_as_uint(f);
  unsigned r = (u + 0x7FFFu + ((u >> 16) & 1u)) >> 16;
  return (unsigned short)r;
}

// ---------------- LN1 over concat(x, toks); writes fp32 a and bf16 a ----------------
__global__ __launch_bounds__(256) void ln1_kernel(
    const float* __restrict__ x, const float* __restrict__ toks,
    const float* __restrict__ g1, const float* __restrict__ b1,
    float* __restrict__ a, unsigned short* __restrict__ abf)
{
  int r = blockIdx.x;                 // 0..8447
  int bb = r / LTOT, t = r - bb*LTOT;
  const float* row = (t < 2048) ? (x + ((size_t)bb*2048 + t)*DM)
                                : (toks + (size_t)(t - 2048)*DM);
  int tid = threadIdx.x;
  float v0 = row[tid], v1 = row[tid + 256];
  float s = v0 + v1, sq = v0*v0 + v1*v1;
  #pragma unroll
  for (int o = 32; o > 0; o >>= 1){ s += __shfl_down(s,o); sq += __shfl_down(sq,o); }
  __shared__ float sb[8];
  if ((tid & 63) == 0){ sb[tid>>6] = s; sb[4 + (tid>>6)] = sq; }
  __syncthreads();
  float S  = sb[0]+sb[1]+sb[2]+sb[3];
  float SQ = sb[4]+sb[5]+sb[6]+sb[7];
  float mean = S * (1.f/DM);
  float var  = SQ * (1.f/DM) - mean*mean;
  float rs = rsqrtf(var + 1e-5f);
  size_t o0 = (size_t)r*DM;
  float r0 = (v0 - mean)*rs*g1[tid]       + b1[tid];
  float r1 = (v1 - mean)*rs*g1[tid + 256] + b1[tid + 256];
  a[o0 + tid]       = r0;
  a[o0 + tid + 256] = r1;
  abf[o0 + tid]       = f2bf(r0);
  abf[o0 + tid + 256] = f2bf(r1);
}

// ---------------- fp32 -> bf16 bulk convert (4 elems/thread) ----------------
__global__ __launch_bounds__(256) void f32_to_bf16_kernel(
    const float* __restrict__ in, unsigned short* __restrict__ out, int n4)
{
  int i = blockIdx.x*256 + threadIdx.x;
  if (i >= n4) return;
  float4 v = reinterpret_cast<const float4*>(in)[i];
  ushort4 o;
  o.x = f2bf(v.x); o.y = f2bf(v.y); o.z = f2bf(v.z); o.w = f2bf(v.w);
  reinterpret_cast<ushort4*>(out)[i] = o;
}

// ---------------- bf16 MFMA GEMM: C[M,N](fp32) = A[M,K] * W[N,K]^T ----------------
// BM=128, BN=64, BK=32, 256 threads (4 waves in 2x2), 16x16x32 MFMA, 4x2 frags/wave.
__global__ __launch_bounds__(256) void gemm_bf16(
    const unsigned short* __restrict__ A, const unsigned short* __restrict__ W,
    float* __restrict__ C, int M, int N, int K, int ldc)
{
  __shared__ unsigned short As[128][40];   // stride 80B: 16B-aligned, 2-way banks (free)
  __shared__ unsigned short Bs[64][40];
  int tid  = threadIdx.x;
  int lane = tid & 63, wid = tid >> 6;
  int wm = wid >> 1, wn = wid & 1;         // 2x2 wave grid
  int l15 = lane & 15, l4 = lane >> 4;
  int m0 = blockIdx.x * 128, n0 = blockIdx.y * 64;
  int sr = tid >> 2, sc = (tid & 3) * 8;   // staging: row, col(elem)

  f32x4 acc[4][2];
  #pragma unroll
  for (int i = 0; i < 4; ++i)
    #pragma unroll
    for (int j = 0; j < 2; ++j) acc[i][j] = (f32x4)0.f;

  for (int k0 = 0; k0 < K; k0 += 32) {
    #pragma unroll
    for (int rr = 0; rr < 2; ++rr) {
      int r = sr + rr*64;
      uint4 v = *reinterpret_cast<const uint4*>(A + (size_t)(m0 + r)*K + k0 + sc);
      *reinterpret_cast<uint4*>(&As[r][sc]) = v;
    }
    {
      int col = n0 + sr;
      uint4 v = make_uint4(0u,0u,0u,0u);
      if (col < N) v = *reinterpret_cast<const uint4*>(W + (size_t)col*K + k0 + sc);
      *reinterpret_cast<uint4*>(&Bs[sr][sc]) = v;
    }
    __syncthreads();
    short8 bfrag[2];
    #pragma unroll
    for (int fn = 0; fn < 2; ++fn)
      bfrag[fn] = *reinterpret_cast<const short8*>(&Bs[wn*32 + fn*16 + l15][l4*8]);
    #pragma unroll
    for (int fm = 0; fm < 4; ++fm) {
      short8 afrag = *reinterpret_cast<const short8*>(&As[wm*64 + fm*16 + l15][l4*8]);
      acc[fm][0] = __builtin_amdgcn_mfma_f32_16x16x32_bf16(afrag, bfrag[0], acc[fm][0], 0, 0, 0);
      acc[fm][1] = __builtin_amdgcn_mfma_f32_16x16x32_bf16(afrag, bfrag[1], acc[fm][1], 0, 0, 0);
    }
    __syncthreads();
  }
  #pragma unroll
  for (int fm = 0; fm < 4; ++fm)
    #pragma unroll
    for (int fn = 0; fn < 2; ++fn) {
      int col = n0 + wn*32 + fn*16 + l15;
      if (col < N)
        #pragma unroll
        for (int j = 0; j < 4; ++j) {
          int row = m0 + wm*64 + fm*16 + l4*4 + j;
          C[(size_t)row*ldc + col] = acc[fm][fn][j];
        }
    }
}

// ---------------- z (gate) for last 64 tokens only: zs = silu(a_row @ Wz^T) ----------------
__global__ __launch_bounds__(256) void z_rows_kernel(
    const float* __restrict__ a, const float* __restrict__ Wz, float* __restrict__ zs)
{
  int rr = blockIdx.x;               // 0..255
  int bb = rr >> 6, tt = rr & 63;
  size_t r = (size_t)bb*LTOT + 2048 + tt;
  __shared__ float as[DM];
  int tid = threadIdx.x;
  as[tid]       = a[r*DM + tid];
  as[tid + 256] = a[r*DM + tid + 256];
  __syncthreads();
  #pragma unroll
  for (int cj = 0; cj < 4; ++cj) {
    int cidx = tid + cj*256;
    const float* wr = Wz + (size_t)cidx*DM;
    float acc = 0.f;
    for (int k = 0; k < DM; k += 4) {
      float4 w4 = *reinterpret_cast<const float4*>(wr + k);
      float4 a4 = *reinterpret_cast<const float4*>(&as[k]);
      acc = fmaf(a4.x,w4.x,acc); acc = fmaf(a4.y,w4.y,acc);
      acc = fmaf(a4.z,w4.z,acc); acc = fmaf(a4.w,w4.w,acc);
    }
    zs[(size_t)rr*DIN + cidx] = fast_silu(acc);
  }
}

// ---------------- causal depthwise conv (K=4) + silu; writes fp32 u and bf16 u ----------------
__global__ __launch_bounds__(256) void conv_silu_kernel(
    const float* __restrict__ upre, const float* __restrict__ Wc,
    const float* __restrict__ bc, float* __restrict__ u, unsigned short* __restrict__ ubf)
{
  size_t idx = (size_t)blockIdx.x*256 + threadIdx.x;   // < 8448*1024
  int d = (int)(idx & 1023);
  int r = (int)(idx >> 10);
  int t = r % LTOT;
  float4 w4 = *reinterpret_cast<const float4*>(Wc + (size_t)d*4);
  float acc = bc[d];
  const float* up = upre + idx;
  if (t >= 3) acc = fmaf(up[-3*DIN], w4.x, acc);
  if (t >= 2) acc = fmaf(up[-2*DIN], w4.y, acc);
  if (t >= 1) acc = fmaf(up[-1*DIN], w4.z, acc);
  acc = fmaf(up[0], w4.w, acc);
  float res = fast_silu(acc);
  u[idx] = res;
  ubf[idx] = f2bf(res);
}

// ---------------- Cm for last 64 tokens: Cm = u_row @ Wxp[288:544]^T ----------------
__global__ __launch_bounds__(256) void c_rows_kernel(
    const float* __restrict__ u, const float* __restrict__ Wxp, float* __restrict__ Cm)
{
  int rr = blockIdx.x;               // 0..255
  int bb = rr >> 6, tt = rr & 63;
  size_t r = (size_t)bb*LTOT + 2048 + tt;
  __shared__ float us[DIN];
  int tid = threadIdx.x;
  #pragma unroll
  for (int j = 0; j < 4; ++j) us[tid + j*256] = u[r*DIN + tid + j*256];
  __syncthreads();
  const float* wr = Wxp + (size_t)(288 + tid)*DIN;
  float acc = 0.f;
  for (int k = 0; k < DIN; k += 4) {
    float4 w4 = *reinterpret_cast<const float4*>(wr + k);
    float4 a4 = *reinterpret_cast<const float4*>(&us[k]);
    acc = fmaf(a4.x,w4.x,acc); acc = fmaf(a4.y,w4.y,acc);
    acc = fmaf(a4.z,w4.z,acc); acc = fmaf(a4.w,w4.w,acc);
  }
  Cm[(size_t)rr*NST + tid] = acc;
}

// ---------------- delta = softplus(dt @ W_dt^T + b_dt); write delta & delta*u TRANSPOSED ----------------
__global__ __launch_bounds__(256) void delta_kernel(
    const float* __restrict__ dbl, const float* __restrict__ W_dt,
    const float* __restrict__ b_dt, const float* __restrict__ u,
    float* __restrict__ deltaT, float* __restrict__ duT)
{
  __shared__ float dts[32][33];
  __shared__ float wds[32][33];
  __shared__ float dT[32][33];
  __shared__ float uT[32][33];
  int r0 = blockIdx.x * 32;
  int d0 = blockIdx.y * 32;
  int bb = r0 / LTOT, t0 = r0 % LTOT;   // 2112 % 32 == 0 -> no batch straddling
  int tid = threadIdx.x;
  #pragma unroll
  for (int p = 0; p < 4; ++p) {
    int o = tid + p*256;
    int rl = o >> 5, j = o & 31;
    dts[rl][j] = dbl[(size_t)(r0 + rl)*288 + j];
    wds[rl][j] = W_dt[(size_t)(d0 + rl)*32 + j];
  }
  __syncthreads();
  #pragma unroll
  for (int p = 0; p < 4; ++p) {
    int o = tid + p*256;
    int dl = o & 31, rl = o >> 5;
    float acc = b_dt[d0 + dl];
    #pragma unroll
    for (int j = 0; j < 32; ++j) acc = fmaf(dts[rl][j], wds[dl][j], acc);
    float delta = (acc > 20.f) ? acc : __logf(1.f + __expf(acc));
    float uu = u[(size_t)(r0 + rl)*DIN + d0 + dl];
    dT[dl][rl] = delta;
    uT[dl][rl] = delta * uu;
  }
  __syncthreads();
  #pragma unroll
  for (int p = 0; p < 4; ++p) {
    int o = tid + p*256;
    int dl = o >> 5, ti = o & 31;
    size_t gi = ((size_t)bb*DIN + d0 + dl)*LTOT + t0 + ti;
    deltaT[gi] = dT[dl][ti];
    duT[gi]    = uT[dl][ti];
  }
}

// ---------------- selective scan: block = (b, 4 consecutive d), thread = n ----------------
__global__ __launch_bounds__(256) void scan_kernel(
    const float* __restrict__ deltaT, const float* __restrict__ duT,
    const float* __restrict__ dbl, const float* __restrict__ Cm,
    const float* __restrict__ A_log, float* __restrict__ y)
{
  int blk = blockIdx.x;          // 0..1023
  int bb = blk >> 8;
  int d0 = (blk & 255) << 2;
  int n = threadIdx.x;
  float Ak[4], h[4] = {0.f,0.f,0.f,0.f};
  #pragma unroll
  for (int g = 0; g < 4; ++g)
    Ak[g] = -__expf(A_log[(size_t)(d0+g)*NST + n]) * 1.44269504089f;  // A*log2(e)
  __shared__ float dc[4][64];
  __shared__ float uc[4][64];
  __shared__ float red[4][4];
  const size_t basebd = ((size_t)bb*DIN + d0)*LTOT;
  const float* Bp = dbl + (size_t)bb*LTOT*288 + 32 + n;
  for (int c = 0; c < 33; ++c) {
    int t0 = c << 6;
    {
      int g = threadIdx.x >> 6, i = threadIdx.x & 63;
      dc[g][i] = deltaT[basebd + (size_t)g*LTOT + t0 + i];
      uc[g][i] = duT  [basebd + (size_t)g*LTOT + t0 + i];
    }
    __syncthreads();
    if (c < 32) {
      #pragma unroll 4
      for (int i = 0; i < 64; ++i) {
        float Bn = Bp[(size_t)(t0 + i)*288];
        #pragma unroll
        for (int g = 0; g < 4; ++g) {
          float dA = exp2f(dc[g][i] * Ak[g]);
          h[g] = fmaf(dA, h[g], uc[g][i] * Bn);
        }
      }
    } else {                      // last 64 timesteps: also produce y = h . C
      for (int i = 0; i < 64; ++i) {
        float Bn = Bp[(size_t)(t0 + i)*288];
        #pragma unroll
        for (int g = 0; g < 4; ++g) {
          float dA = exp2f(dc[g][i] * Ak[g]);
          h[g] = fmaf(dA, h[g], uc[g][i] * Bn);
        }
        float Cn = Cm[((size_t)(bb*64 + i))*NST + n];
        #pragma unroll
        for (int g = 0; g < 4; ++g) {
          float v = h[g] * Cn;
          #pragma unroll
          for (int o = 32; o > 0; o >>= 1) v += __shfl_down(v, o);
          if ((threadIdx.x & 63) == 0) red[threadIdx.x >> 6][g] = v;
        }
        __syncthreads();
        if (threadIdx.x < 4) {
          float sv = red[0][threadIdx.x] + red[1][threadIdx.x]
                   + red[2][threadIdx.x] + red[3][threadIdx.x];
          y[((size_t)(bb*64 + i))*DIN + d0 + threadIdx.x] = sv;
        }
        __syncthreads();
      }
    }
    __syncthreads();
  }
}

// ---------------- y2 = (y_scan + u*Dp) * silu(z) ----------------
__global__ __launch_bounds__(256) void y2_kernel(
    const float* __restrict__ y, const float* __restrict__ u, const float* __restrict__ zs,
    const float* __restrict__ Dp, float* __restrict__ y2)
{
  int idx = blockIdx.x*256 + threadIdx.x;  // < 262144
  int rr = idx >> 10, d = idx & 1023;
  int bb = rr >> 6, tt = rr & 63;
  size_t r = (size_t)bb*LTOT + 2048 + tt;
  float yv = y[idx] + u[r*DIN + d] * Dp[d];
  y2[idx] = yv * zs[idx];
}

// ---------------- out_proj + residual (residual row = fused token) ----------------
__global__ __launch_bounds__(256) void outproj_kernel(
    const float* __restrict__ y2, const float* __restrict__ Wout,
    const float* __restrict__ toks, float* __restrict__ hfin)
{
  __shared__ float ys[4][DIN];
  int rb = blockIdx.x;                 // 64 blocks, 4 rows each
  int tid = threadIdx.x;
  #pragma unroll
  for (int rr = 0; rr < 4; ++rr)
    #pragma unroll
    for (int j = 0; j < 4; ++j)
      ys[rr][tid + j*256] = y2[(size_t)(rb*4 + rr)*DIN + tid + j*256];
  __syncthreads();
  #pragma unroll
  for (int cj = 0; cj < 2; ++cj) {
    int cidx = tid + cj*256;
    const float* wr = Wout + (size_t)cidx*DIN;
    float a0=0.f,a1=0.f,a2=0.f,a3=0.f;
    for (int k = 0; k < DIN; k += 4) {
      float4 w4 = *reinterpret_cast<const float4*>(wr + k);
      float4 r0 = *reinterpret_cast<const float4*>(&ys[0][k]);
      float4 r1 = *reinterpret_cast<const float4*>(&ys[1][k]);
      float4 r2 = *reinterpret_cast<const float4*>(&ys[2][k]);
      float4 r3 = *reinterpret_cast<const float4*>(&ys[3][k]);
      a0=fmaf(r0.x,w4.x,a0); a0=fmaf(r0.y,w4.y,a0); a0=fmaf(r0.z,w4.z,a0); a0=fmaf(r0.w,w4.w,a0);
      a1=fmaf(r1.x,w4.x,a1); a1=fmaf(r1.y,w4.y,a1); a1=fmaf(r1.z,w4.z,a1); a1=fmaf(r1.w,w4.w,a1);
      a2=fmaf(r2.x,w4.x,a2); a2=fmaf(r2.y,w4.y,a2); a2=fmaf(r2.z,w4.z,a2); a2=fmaf(r2.w,w4.w,a2);
      a3=fmaf(r3.x,w4.x,a3); a3=fmaf(r3.y,w4.y,a3); a3=fmaf(r3.z,w4.z,a3); a3=fmaf(r3.w,w4.w,a3);
    }
    float accs[4] = {a0,a1,a2,a3};
    #pragma unroll
    for (int rr = 0; rr < 4; ++rr) {
      int rg = rb*4 + rr;
      hfin[(size_t)rg*DM + cidx] = accs[rr] + toks[(size_t)(rg & 63)*DM + cidx];
    }
  }
}

// ---------------- LN2 + head GEMM + residual ----------------
__global__ __launch_bounds__(256) void head_kernel(
    const float* __restrict__ hfin, const float* __restrict__ g2, const float* __restrict__ b2,
    const float* __restrict__ Wh, const float* __restrict__ bh, float* __restrict__ out)
{
  int rr = blockIdx.x;                 // 0..255
  int tid = threadIdx.x;
  float v0 = hfin[(size_t)rr*DM + tid];
  float v1 = hfin[(size_t)rr*DM + tid + 256];
  float s = v0 + v1, sq = v0*v0 + v1*v1;
  #pragma unroll
  for (int o = 32; o > 0; o >>= 1){ s += __shfl_down(s,o); sq += __shfl_down(sq,o); }
  __shared__ float sb[8];
  if ((tid & 63) == 0){ sb[tid>>6] = s; sb[4 + (tid>>6)] = sq; }
  __syncthreads();
  float S  = sb[0]+sb[1]+sb[2]+sb[3];
  float SQ = sb[4]+sb[5]+sb[6]+sb[7];
  float mean = S * (1.f/DM);
  float rs = rsqrtf(SQ * (1.f/DM) - mean*mean + 1e-5f);
  __shared__ float as[DM];
  as[tid]       = (v0 - mean)*rs*g2[tid]       + b2[tid];
  as[tid + 256] = (v1 - mean)*rs*g2[tid + 256] + b2[tid + 256];
  __syncthreads();
  #pragma unroll
  for (int cj = 0; cj < 2; ++cj) {
    int cidx = tid + cj*256;
    const float* wr = Wh + (size_t)cidx*DM;
    float acc = bh[cidx] + (cj ? v1 : v0);
    for (int k = 0; k < DM; k += 4) {
      float4 w4 = *reinterpret_cast<const float4*>(wr + k);
      float4 a4 = *reinterpret_cast<const float4*>(&as[k]);
      acc = fmaf(a4.x,w4.x,acc); acc = fmaf(a4.y,w4.y,acc);
      acc = fmaf(a4.z,w4.z,acc); acc = fmaf(a4.w,w4.w,acc);
    }
    out[(size_t)rr*DM + cidx] = acc;
  }
}

extern "C" void kernel_launch(void* const* d_in, const int* in_sizes, int n_in,
                              void* d_out, int out_size, void* d_ws, size_t ws_size,
                              hipStream_t stream) {
  const float* x      = (const float*)d_in[0];
  const float* toks   = (const float*)d_in[1];
  const float* g1     = (const float*)d_in[2];
  const float* b1     = (const float*)d_in[3];
  const float* g2     = (const float*)d_in[4];
  const float* b2     = (const float*)d_in[5];
  const float* W_head = (const float*)d_in[6];
  const float* b_head = (const float*)d_in[7];
  const float* W_in   = (const float*)d_in[8];
  const float* W_conv = (const float*)d_in[9];
  const float* b_conv = (const float*)d_in[10];
  const float* W_xp   = (const float*)d_in[11];
  const float* W_dt   = (const float*)d_in[12];
  const float* b_dt   = (const float*)d_in[13];
  const float* A_log  = (const float*)d_in[14];
  const float* Dp     = (const float*)d_in[15];
  const float* W_out  = (const float*)d_in[16];

  float* ws = (float*)d_ws;
  float* a_buf   = ws;                                  // 8448*512
  float* u_pre   = a_buf   + (size_t)NROWS*DM;          // 8448*1024 (reused as deltaT)
  float* u_buf   = u_pre   + (size_t)NROWS*DIN;         // 8448*1024
  float* dbl_buf = u_buf   + (size_t)NROWS*DIN;         // 8448*288
  float* duT     = dbl_buf + (size_t)NROWS*288;         // 8448*1024
  float* zs      = duT     + (size_t)NROWS*DIN;         // 256*1024
  float* Cm      = zs      + (size_t)256*DIN;           // 256*256
  float* y_buf   = Cm      + (size_t)256*NST;           // 256*1024
  float* y2_buf  = y_buf   + (size_t)256*DIN;           // 256*1024
  float* hfin    = y2_buf  + (size_t)256*DIN;           // 256*512
  float* deltaT  = u_pre;                               // overlay (u_pre dead after conv)

  // bf16 staging buffers overlay duT (dead until delta_kernel runs):
  // a_bf16: NROWS*DM ushort (8.65MB) ; u_bf16: NROWS*DIN ushort (17.3MB);
  // wi_bf16: DIN*DM ushort ; wx_bf16: 288*DIN ushort.  Total 27.6MB < duT's 34.6MB.
  unsigned short* a_bf16  = (unsigned short*)duT;
  unsigned short* u_bf16  = a_bf16 + (size_t)NROWS*DM;
  unsigned short* wi_bf16 = u_bf16 + (size_t)NROWS*DIN;
  unsigned short* wx_bf16 = wi_bf16 + (size_t)DIN*DM;

  // weight conversions (u-half of W_in; dt+B rows of W_xp)
  f32_to_bf16_kernel<<<(DIN*DM/4 + 255)/256, 256, 0, stream>>>(W_in, wi_bf16, DIN*DM/4);
  f32_to_bf16_kernel<<<(288*DIN/4 + 255)/256, 256, 0, stream>>>(W_xp, wx_bf16, 288*DIN/4);

  ln1_kernel<<<NROWS, 256, 0, stream>>>(x, toks, g1, b1, a_buf, a_bf16);
  gemm_bf16<<<dim3(NROWS/128, DIN/64), 256, 0, stream>>>(a_bf16, wi_bf16, u_pre,
                                                         NROWS, DIN, DM, DIN);
  z_rows_kernel<<<256, 256, 0, stream>>>(a_buf, W_in + (size_t)DIN*DM, zs);
  conv_silu_kernel<<<(NROWS*DIN)/256, 256, 0, stream>>>(u_pre, W_conv, b_conv, u_buf, u_bf16);
  gemm_bf16<<<dim3(NROWS/128, (288 + 63)/64), 256, 0, stream>>>(u_bf16, wx_bf16, dbl_buf,
                                                                NROWS, 288, DIN, 288);
  c_rows_kernel<<<256, 256, 0, stream>>>(u_buf, W_xp, Cm);
  delta_kernel<<<dim3(NROWS/32, DIN/32), 256, 0, stream>>>(dbl_buf, W_dt, b_dt, u_buf,
                                                           deltaT, duT);
  scan_kernel<<<1024, 256, 0, stream>>>(deltaT, duT, dbl_buf, Cm, A_log, y_buf);
  y2_kernel<<<1024, 256, 0, stream>>>(y_buf, u_buf, zs, Dp, y2_buf);
  outproj_kernel<<<64, 256, 0, stream>>>(y2_buf, W_out, toks, hfin);
  head_kernel<<<256, 256, 0, stream>>>(hfin, g2, b2, W_head, b_head, (float*)d_out);
}

// Round 4
// 839.669 us; speedup vs baseline: 1.2644x; 1.2644x over previous
//
#include <hip/hip_runtime.h>

#define LTOT 2112
#define NROWS 8448   // 4 * 2112
#define DM 512
#define DIN 1024
#define NST 256

using short8 = short  __attribute__((ext_vector_type(8)));
using f32x4  = float  __attribute__((ext_vector_type(4)));

__device__ __forceinline__ float fast_silu(float x){ return x / (1.f + __expf(-x)); }

__device__ __forceinline__ unsigned short f2bf(float f){
  unsigned u = __float_as_uint(f);
  unsigned r = (u + 0x7FFFu + ((u >> 16) & 1u)) >> 16;
  return (unsigned short)r;
}

// ---------------- LN1 over concat(x, toks); writes fp32 a and bf16 a ----------------
__global__ __launch_bounds__(256) void ln1_kernel(
    const float* __restrict__ x, const float* __restrict__ toks,
    const float* __restrict__ g1, const float* __restrict__ b1,
    float* __restrict__ a, unsigned short* __restrict__ abf)
{
  int r = blockIdx.x;                 // 0..8447
  int bb = r / LTOT, t = r - bb*LTOT;
  const float* row = (t < 2048) ? (x + ((size_t)bb*2048 + t)*DM)
                                : (toks + (size_t)(t - 2048)*DM);
  int tid = threadIdx.x;
  float v0 = row[tid], v1 = row[tid + 256];
  float s = v0 + v1, sq = v0*v0 + v1*v1;
  #pragma unroll
  for (int o = 32; o > 0; o >>= 1){ s += __shfl_down(s,o); sq += __shfl_down(sq,o); }
  __shared__ float sb[8];
  if ((tid & 63) == 0){ sb[tid>>6] = s; sb[4 + (tid>>6)] = sq; }
  __syncthreads();
  float S  = sb[0]+sb[1]+sb[2]+sb[3];
  float SQ = sb[4]+sb[5]+sb[6]+sb[7];
  float mean = S * (1.f/DM);
  float var  = SQ * (1.f/DM) - mean*mean;
  float rs = rsqrtf(var + 1e-5f);
  size_t o0 = (size_t)r*DM;
  float r0 = (v0 - mean)*rs*g1[tid]       + b1[tid];
  float r1 = (v1 - mean)*rs*g1[tid + 256] + b1[tid + 256];
  a[o0 + tid]       = r0;
  a[o0 + tid + 256] = r1;
  abf[o0 + tid]       = f2bf(r0);
  abf[o0 + tid + 256] = f2bf(r1);
}

// ---------------- fp32 -> bf16 bulk convert (4 elems/thread) ----------------
__global__ __launch_bounds__(256) void f32_to_bf16_kernel(
    const float* __restrict__ in, unsigned short* __restrict__ out, int n4)
{
  int i = blockIdx.x*256 + threadIdx.x;
  if (i >= n4) return;
  float4 v = reinterpret_cast<const float4*>(in)[i];
  ushort4 o;
  o.x = f2bf(v.x); o.y = f2bf(v.y); o.z = f2bf(v.z); o.w = f2bf(v.w);
  reinterpret_cast<ushort4*>(out)[i] = o;
}

// ---------------- bf16 MFMA GEMM: C[M,N](fp32) = A[M,K] * W[N,K]^T ----------------
// BM=128, BN=64, BK=32, 256 threads (4 waves in 2x2), 16x16x32 MFMA, 4x2 frags/wave.
__global__ __launch_bounds__(256) void gemm_bf16(
    const unsigned short* __restrict__ A, const unsigned short* __restrict__ W,
    float* __restrict__ C, int M, int N, int K, int ldc)
{
  __shared__ unsigned short As[128][40];   // stride 80B: 16B-aligned, 2-way banks (free)
  __shared__ unsigned short Bs[64][40];
  int tid  = threadIdx.x;
  int lane = tid & 63, wid = tid >> 6;
  int wm = wid >> 1, wn = wid & 1;         // 2x2 wave grid
  int l15 = lane & 15, l4 = lane >> 4;
  int m0 = blockIdx.x * 128, n0 = blockIdx.y * 64;
  int sr = tid >> 2, sc = (tid & 3) * 8;   // staging: row, col(elem)

  f32x4 acc[4][2];
  #pragma unroll
  for (int i = 0; i < 4; ++i)
    #pragma unroll
    for (int j = 0; j < 2; ++j) acc[i][j] = (f32x4)0.f;

  for (int k0 = 0; k0 < K; k0 += 32) {
    #pragma unroll
    for (int rr = 0; rr < 2; ++rr) {
      int r = sr + rr*64;
      uint4 v = *reinterpret_cast<const uint4*>(A + (size_t)(m0 + r)*K + k0 + sc);
      *reinterpret_cast<uint4*>(&As[r][sc]) = v;
    }
    {
      int col = n0 + sr;
      uint4 v = make_uint4(0u,0u,0u,0u);
      if (col < N) v = *reinterpret_cast<const uint4*>(W + (size_t)col*K + k0 + sc);
      *reinterpret_cast<uint4*>(&Bs[sr][sc]) = v;
    }
    __syncthreads();
    short8 bfrag[2];
    #pragma unroll
    for (int fn = 0; fn < 2; ++fn)
      bfrag[fn] = *reinterpret_cast<const short8*>(&Bs[wn*32 + fn*16 + l15][l4*8]);
    #pragma unroll
    for (int fm = 0; fm < 4; ++fm) {
      short8 afrag = *reinterpret_cast<const short8*>(&As[wm*64 + fm*16 + l15][l4*8]);
      acc[fm][0] = __builtin_amdgcn_mfma_f32_16x16x32_bf16(afrag, bfrag[0], acc[fm][0], 0, 0, 0);
      acc[fm][1] = __builtin_amdgcn_mfma_f32_16x16x32_bf16(afrag, bfrag[1], acc[fm][1], 0, 0, 0);
    }
    __syncthreads();
  }
  #pragma unroll
  for (int fm = 0; fm < 4; ++fm)
    #pragma unroll
    for (int fn = 0; fn < 2; ++fn) {
      int col = n0 + wn*32 + fn*16 + l15;
      if (col < N)
        #pragma unroll
        for (int j = 0; j < 4; ++j) {
          int row = m0 + wm*64 + fm*16 + l4*4 + j;
          C[(size_t)row*ldc + col] = acc[fm][fn][j];
        }
    }
}

// ---------------- z (gate) for last 64 tokens only: zs = silu(a_row @ Wz^T) ----------------
__global__ __launch_bounds__(256) void z_rows_kernel(
    const float* __restrict__ a, const float* __restrict__ Wz, float* __restrict__ zs)
{
  int rr = blockIdx.x;               // 0..255
  int bb = rr >> 6, tt = rr & 63;
  size_t r = (size_t)bb*LTOT + 2048 + tt;
  __shared__ float as[DM];
  int tid = threadIdx.x;
  as[tid]       = a[r*DM + tid];
  as[tid + 256] = a[r*DM + tid + 256];
  __syncthreads();
  #pragma unroll
  for (int cj = 0; cj < 4; ++cj) {
    int cidx = tid + cj*256;
    const float* wr = Wz + (size_t)cidx*DM;
    float acc = 0.f;
    for (int k = 0; k < DM; k += 4) {
      float4 w4 = *reinterpret_cast<const float4*>(wr + k);
      float4 a4 = *reinterpret_cast<const float4*>(&as[k]);
      acc = fmaf(a4.x,w4.x,acc); acc = fmaf(a4.y,w4.y,acc);
      acc = fmaf(a4.z,w4.z,acc); acc = fmaf(a4.w,w4.w,acc);
    }
    zs[(size_t)rr*DIN + cidx] = fast_silu(acc);
  }
}

// ---------------- causal depthwise conv (K=4) + silu; writes fp32 u and bf16 u ----------------
__global__ __launch_bounds__(256) void conv_silu_kernel(
    const float* __restrict__ upre, const float* __restrict__ Wc,
    const float* __restrict__ bc, float* __restrict__ u, unsigned short* __restrict__ ubf)
{
  size_t idx = (size_t)blockIdx.x*256 + threadIdx.x;   // < 8448*1024
  int d = (int)(idx & 1023);
  int r = (int)(idx >> 10);
  int t = r % LTOT;
  float4 w4 = *reinterpret_cast<const float4*>(Wc + (size_t)d*4);
  float acc = bc[d];
  const float* up = upre + idx;
  if (t >= 3) acc = fmaf(up[-3*DIN], w4.x, acc);
  if (t >= 2) acc = fmaf(up[-2*DIN], w4.y, acc);
  if (t >= 1) acc = fmaf(up[-1*DIN], w4.z, acc);
  acc = fmaf(up[0], w4.w, acc);
  float res = fast_silu(acc);
  u[idx] = res;
  ubf[idx] = f2bf(res);
}

// ---------------- Cm for last 64 tokens: Cm = u_row @ Wxp[288:544]^T ----------------
__global__ __launch_bounds__(256) void c_rows_kernel(
    const float* __restrict__ u, const float* __restrict__ Wxp, float* __restrict__ Cm)
{
  int rr = blockIdx.x;               // 0..255
  int bb = rr >> 6, tt = rr & 63;
  size_t r = (size_t)bb*LTOT + 2048 + tt;
  __shared__ float us[DIN];
  int tid = threadIdx.x;
  #pragma unroll
  for (int j = 0; j < 4; ++j) us[tid + j*256] = u[r*DIN + tid + j*256];
  __syncthreads();
  const float* wr = Wxp + (size_t)(288 + tid)*DIN;
  float acc = 0.f;
  for (int k = 0; k < DIN; k += 4) {
    float4 w4 = *reinterpret_cast<const float4*>(wr + k);
    float4 a4 = *reinterpret_cast<const float4*>(&us[k]);
    acc = fmaf(a4.x,w4.x,acc); acc = fmaf(a4.y,w4.y,acc);
    acc = fmaf(a4.z,w4.z,acc); acc = fmaf(a4.w,w4.w,acc);
  }
  Cm[(size_t)rr*NST + tid] = acc;
}

// ---------------- delta = softplus(dt @ W_dt^T + b_dt); write delta & delta*u TRANSPOSED ----------------
__global__ __launch_bounds__(256) void delta_kernel(
    const float* __restrict__ dbl, const float* __restrict__ W_dt,
    const float* __restrict__ b_dt, const float* __restrict__ u,
    float* __restrict__ deltaT, float* __restrict__ duT)
{
  __shared__ float dts[32][33];
  __shared__ float wds[32][33];
  __shared__ float dT[32][33];
  __shared__ float uT[32][33];
  int r0 = blockIdx.x * 32;
  int d0 = blockIdx.y * 32;
  int bb = r0 / LTOT, t0 = r0 % LTOT;   // 2112 % 32 == 0 -> no batch straddling
  int tid = threadIdx.x;
  #pragma unroll
  for (int p = 0; p < 4; ++p) {
    int o = tid + p*256;
    int rl = o >> 5, j = o & 31;
    dts[rl][j] = dbl[(size_t)(r0 + rl)*288 + j];
    wds[rl][j] = W_dt[(size_t)(d0 + rl)*32 + j];
  }
  __syncthreads();
  #pragma unroll
  for (int p = 0; p < 4; ++p) {
    int o = tid + p*256;
    int dl = o & 31, rl = o >> 5;
    float acc = b_dt[d0 + dl];
    #pragma unroll
    for (int j = 0; j < 32; ++j) acc = fmaf(dts[rl][j], wds[dl][j], acc);
    float delta = (acc > 20.f) ? acc : __logf(1.f + __expf(acc));
    float uu = u[(size_t)(r0 + rl)*DIN + d0 + dl];
    dT[dl][rl] = delta;
    uT[dl][rl] = delta * uu;
  }
  __syncthreads();
  #pragma unroll
  for (int p = 0; p < 4; ++p) {
    int o = tid + p*256;
    int dl = o >> 5, ti = o & 31;
    size_t gi = ((size_t)bb*DIN + d0 + dl)*LTOT + t0 + ti;
    deltaT[gi] = dT[dl][ti];
    duT[gi]    = uT[dl][ti];
  }
}

// ---------------- selective scan v2: no LDS staging; wave-uniform scalar loads ----------------
// block = (b, 4 consecutive d), thread = n. delta/du reads are uniform across the
// block (address independent of threadIdx) -> lowered to s_load (scalar pipe),
// freeing VALU/LDS issue slots. B-row loads stay coalesced per-lane.
__global__ __launch_bounds__(256) void scan_kernel(
    const float* __restrict__ deltaT, const float* __restrict__ duT,
    const float* __restrict__ dbl, const float* __restrict__ Cm,
    const float* __restrict__ A_log, float* __restrict__ y)
{
  int blk = blockIdx.x;          // 0..1023
  int bb = blk >> 8;
  int d0 = (blk & 255) << 2;
  int n = threadIdx.x;
  float Ak[4], h[4] = {0.f,0.f,0.f,0.f};
  #pragma unroll
  for (int g = 0; g < 4; ++g) {
    float al = A_log[(size_t)(d0+g)*NST + n];
    // A = exp(A_log); Ak = A * log2(e) (negated)
    Ak[g] = -__builtin_amdgcn_exp2f(al * 1.44269504089f) * 1.44269504089f;
  }
  const size_t basebd = ((size_t)bb*DIN + d0)*LTOT;
  const float* __restrict__ pd = deltaT + basebd;   // uniform base
  const float* __restrict__ pu = duT    + basebd;
  const float* __restrict__ Bp = dbl + (size_t)bb*LTOT*288 + 32 + n;

  // ---- fast phase: t in [0, 2048), 4 timesteps per iteration ----
  for (int t0c = 0; t0c < 2048; t0c += 4) {
    float Bnv[4];
    #pragma unroll
    for (int i = 0; i < 4; ++i) Bnv[i] = Bp[(size_t)(t0c + i)*288];
    float dv[4][4], uv[4][4];
    #pragma unroll
    for (int g = 0; g < 4; ++g) {
      float4 dq = *reinterpret_cast<const float4*>(pd + (size_t)g*LTOT + t0c);
      float4 uq = *reinterpret_cast<const float4*>(pu + (size_t)g*LTOT + t0c);
      dv[g][0]=dq.x; dv[g][1]=dq.y; dv[g][2]=dq.z; dv[g][3]=dq.w;
      uv[g][0]=uq.x; uv[g][1]=uq.y; uv[g][2]=uq.z; uv[g][3]=uq.w;
    }
    #pragma unroll
    for (int i = 0; i < 4; ++i) {
      float Bn = Bnv[i];
      #pragma unroll
      for (int g = 0; g < 4; ++g) {
        float dA = __builtin_amdgcn_exp2f(dv[g][i] * Ak[g]);
        h[g] = fmaf(dA, h[g], uv[g][i] * Bn);
      }
    }
  }

  // ---- readout phase: last 64 timesteps, also y = h . C ----
  __shared__ float red[4][4];
  for (int t = 2048; t < 2112; ++t) {
    float Bn = Bp[(size_t)t*288];
    #pragma unroll
    for (int g = 0; g < 4; ++g) {
      float dA = __builtin_amdgcn_exp2f(pd[(size_t)g*LTOT + t] * Ak[g]);
      h[g] = fmaf(dA, h[g], pu[(size_t)g*LTOT + t] * Bn);
    }
    float Cn = Cm[((size_t)(bb*64 + (t - 2048)))*NST + n];
    #pragma unroll
    for (int g = 0; g < 4; ++g) {
      float v = h[g] * Cn;
      #pragma unroll
      for (int o = 32; o > 0; o >>= 1) v += __shfl_down(v, o);
      if ((threadIdx.x & 63) == 0) red[threadIdx.x >> 6][g] = v;
    }
    __syncthreads();
    if (threadIdx.x < 4) {
      float sv = red[0][threadIdx.x] + red[1][threadIdx.x]
               + red[2][threadIdx.x] + red[3][threadIdx.x];
      y[((size_t)(bb*64 + (t - 2048)))*DIN + d0 + threadIdx.x] = sv;
    }
    __syncthreads();
  }
}

// ---------------- y2 = (y_scan + u*Dp) * silu(z) ----------------
__global__ __launch_bounds__(256) void y2_kernel(
    const float* __restrict__ y, const float* __restrict__ u, const float* __restrict__ zs,
    const float* __restrict__ Dp, float* __restrict__ y2)
{
  int idx = blockIdx.x*256 + threadIdx.x;  // < 262144
  int rr = idx >> 10, d = idx & 1023;
  int bb = rr >> 6, tt = rr & 63;
  size_t r = (size_t)bb*LTOT + 2048 + tt;
  float yv = y[idx] + u[r*DIN + d] * Dp[d];
  y2[idx] = yv * zs[idx];
}

// ---------------- out_proj + residual (residual row = fused token) ----------------
__global__ __launch_bounds__(256) void outproj_kernel(
    const float* __restrict__ y2, const float* __restrict__ Wout,
    const float* __restrict__ toks, float* __restrict__ hfin)
{
  __shared__ float ys[4][DIN];
  int rb = blockIdx.x;                 // 64 blocks, 4 rows each
  int tid = threadIdx.x;
  #pragma unroll
  for (int rr = 0; rr < 4; ++rr)
    #pragma unroll
    for (int j = 0; j < 4; ++j)
      ys[rr][tid + j*256] = y2[(size_t)(rb*4 + rr)*DIN + tid + j*256];
  __syncthreads();
  #pragma unroll
  for (int cj = 0; cj < 2; ++cj) {
    int cidx = tid + cj*256;
    const float* wr = Wout + (size_t)cidx*DIN;
    float a0=0.f,a1=0.f,a2=0.f,a3=0.f;
    for (int k = 0; k < DIN; k += 4) {
      float4 w4 = *reinterpret_cast<const float4*>(wr + k);
      float4 r0 = *reinterpret_cast<const float4*>(&ys[0][k]);
      float4 r1 = *reinterpret_cast<const float4*>(&ys[1][k]);
      float4 r2 = *reinterpret_cast<const float4*>(&ys[2][k]);
      float4 r3 = *reinterpret_cast<const float4*>(&ys[3][k]);
      a0=fmaf(r0.x,w4.x,a0); a0=fmaf(r0.y,w4.y,a0); a0=fmaf(r0.z,w4.z,a0); a0=fmaf(r0.w,w4.w,a0);
      a1=fmaf(r1.x,w4.x,a1); a1=fmaf(r1.y,w4.y,a1); a1=fmaf(r1.z,w4.z,a1); a1=fmaf(r1.w,w4.w,a1);
      a2=fmaf(r2.x,w4.x,a2); a2=fmaf(r2.y,w4.y,a2); a2=fmaf(r2.z,w4.z,a2); a2=fmaf(r2.w,w4.w,a2);
      a3=fmaf(r3.x,w4.x,a3); a3=fmaf(r3.y,w4.y,a3); a3=fmaf(r3.z,w4.z,a3); a3=fmaf(r3.w,w4.w,a3);
    }
    float accs[4] = {a0,a1,a2,a3};
    #pragma unroll
    for (int rr = 0; rr < 4; ++rr) {
      int rg = rb*4 + rr;
      hfin[(size_t)rg*DM + cidx] = accs[rr] + toks[(size_t)(rg & 63)*DM + cidx];
    }
  }
}

// ---------------- LN2 + head GEMM + residual ----------------
__global__ __launch_bounds__(256) void head_kernel(
    const float* __restrict__ hfin, const float* __restrict__ g2, const float* __restrict__ b2,
    const float* __restrict__ Wh, const float* __restrict__ bh, float* __restrict__ out)
{
  int rr = blockIdx.x;                 // 0..255
  int tid = threadIdx.x;
  float v0 = hfin[(size_t)rr*DM + tid];
  float v1 = hfin[(size_t)rr*DM + tid + 256];
  float s = v0 + v1, sq = v0*v0 + v1*v1;
  #pragma unroll
  for (int o = 32; o > 0; o >>= 1){ s += __shfl_down(s,o); sq += __shfl_down(sq,o); }
  __shared__ float sb[8];
  if ((tid & 63) == 0){ sb[tid>>6] = s; sb[4 + (tid>>6)] = sq; }
  __syncthreads();
  float S  = sb[0]+sb[1]+sb[2]+sb[3];
  float SQ = sb[4]+sb[5]+sb[6]+sb[7];
  float mean = S * (1.f/DM);
  float rs = rsqrtf(SQ * (1.f/DM) - mean*mean + 1e-5f);
  __shared__ float as[DM];
  as[tid]       = (v0 - mean)*rs*g2[tid]       + b2[tid];
  as[tid + 256] = (v1 - mean)*rs*g2[tid + 256] + b2[tid + 256];
  __syncthreads();
  #pragma unroll
  for (int cj = 0; cj < 2; ++cj) {
    int cidx = tid + cj*256;
    const float* wr = Wh + (size_t)cidx*DM;
    float acc = bh[cidx] + (cj ? v1 : v0);
    for (int k = 0; k < DM; k += 4) {
      float4 w4 = *reinterpret_cast<const float4*>(wr + k);
      float4 a4 = *reinterpret_cast<const float4*>(&as[k]);
      acc = fmaf(a4.x,w4.x,acc); acc = fmaf(a4.y,w4.y,acc);
      acc = fmaf(a4.z,w4.z,acc); acc = fmaf(a4.w,w4.w,acc);
    }
    out[(size_t)rr*DM + cidx] = acc;
  }
}

extern "C" void kernel_launch(void* const* d_in, const int* in_sizes, int n_in,
                              void* d_out, int out_size, void* d_ws, size_t ws_size,
                              hipStream_t stream) {
  const float* x      = (const float*)d_in[0];
  const float* toks   = (const float*)d_in[1];
  const float* g1     = (const float*)d_in[2];
  const float* b1     = (const float*)d_in[3];
  const float* g2     = (const float*)d_in[4];
  const float* b2     = (const float*)d_in[5];
  const float* W_head = (const float*)d_in[6];
  const float* b_head = (const float*)d_in[7];
  const float* W_in   = (const float*)d_in[8];
  const float* W_conv = (const float*)d_in[9];
  const float* b_conv = (const float*)d_in[10];
  const float* W_xp   = (const float*)d_in[11];
  const float* W_dt   = (const float*)d_in[12];
  const float* b_dt   = (const float*)d_in[13];
  const float* A_log  = (const float*)d_in[14];
  const float* Dp     = (const float*)d_in[15];
  const float* W_out  = (const float*)d_in[16];

  float* ws = (float*)d_ws;
  float* a_buf   = ws;                                  // 8448*512
  float* u_pre   = a_buf   + (size_t)NROWS*DM;          // 8448*1024 (reused as deltaT)
  float* u_buf   = u_pre   + (size_t)NROWS*DIN;         // 8448*1024
  float* dbl_buf = u_buf   + (size_t)NROWS*DIN;         // 8448*288
  float* duT     = dbl_buf + (size_t)NROWS*288;         // 8448*1024
  float* zs      = duT     + (size_t)NROWS*DIN;         // 256*1024
  float* Cm      = zs      + (size_t)256*DIN;           // 256*256
  float* y_buf   = Cm      + (size_t)256*NST;           // 256*1024
  float* y2_buf  = y_buf   + (size_t)256*DIN;           // 256*1024
  float* hfin    = y2_buf  + (size_t)256*DIN;           // 256*512
  float* deltaT  = u_pre;                               // overlay (u_pre dead after conv)

  // bf16 staging buffers overlay duT (dead until delta_kernel runs):
  unsigned short* a_bf16  = (unsigned short*)duT;
  unsigned short* u_bf16  = a_bf16 + (size_t)NROWS*DM;
  unsigned short* wi_bf16 = u_bf16 + (size_t)NROWS*DIN;
  unsigned short* wx_bf16 = wi_bf16 + (size_t)DIN*DM;

  f32_to_bf16_kernel<<<(DIN*DM/4 + 255)/256, 256, 0, stream>>>(W_in, wi_bf16, DIN*DM/4);
  f32_to_bf16_kernel<<<(288*DIN/4 + 255)/256, 256, 0, stream>>>(W_xp, wx_bf16, 288*DIN/4);

  ln1_kernel<<<NROWS, 256, 0, stream>>>(x, toks, g1, b1, a_buf, a_bf16);
  gemm_bf16<<<dim3(NROWS/128, DIN/64), 256, 0, stream>>>(a_bf16, wi_bf16, u_pre,
                                                         NROWS, DIN, DM, DIN);
  z_rows_kernel<<<256, 256, 0, stream>>>(a_buf, W_in + (size_t)DIN*DM, zs);
  conv_silu_kernel<<<(NROWS*DIN)/256, 256, 0, stream>>>(u_pre, W_conv, b_conv, u_buf, u_bf16);
  gemm_bf16<<<dim3(NROWS/128, (288 + 63)/64), 256, 0, stream>>>(u_bf16, wx_bf16, dbl_buf,
                                                                NROWS, 288, DIN, 288);
  c_rows_kernel<<<256, 256, 0, stream>>>(u_buf, W_xp, Cm);
  delta_kernel<<<dim3(NROWS/32, DIN/32), 256, 0, stream>>>(dbl_buf, W_dt, b_dt, u_buf,
                                                           deltaT, duT);
  scan_kernel<<<1024, 256, 0, stream>>>(deltaT, duT, dbl_buf, Cm, A_log, y_buf);
  y2_kernel<<<1024, 256, 0, stream>>>(y_buf, u_buf, zs, Dp, y2_buf);
  outproj_kernel<<<64, 256, 0, stream>>>(y2_buf, W_out, toks, hfin);
  head_kernel<<<256, 256, 0, stream>>>(hfin, g2, b2, W_head, b_head, (float*)d_out);
}

// Round 11
// 709.063 us; speedup vs baseline: 1.4973x; 1.1842x over previous
//
#include <hip/hip_runtime.h>

#define LTOT 2112
#define NROWS 8448   // 4 * 2112
#define DM 512
#define DIN 1024
#define NST 256

using short8 = short  __attribute__((ext_vector_type(8)));
using f32x4  = float  __attribute__((ext_vector_type(4)));

__device__ __forceinline__ float fast_silu(float x){ return x / (1.f + __expf(-x)); }

__device__ __forceinline__ unsigned short f2bf(float f){
  unsigned u = __float_as_uint(f);
  unsigned r = (u + 0x7FFFu + ((u >> 16) & 1u)) >> 16;
  return (unsigned short)r;
}

// ---------------- LN1 over concat(x, toks); fp32 a, bf16 a, compact bf16 last-64 rows ----------------
__global__ __launch_bounds__(256) void ln1_kernel(
    const float* __restrict__ x, const float* __restrict__ toks,
    const float* __restrict__ g1, const float* __restrict__ b1,
    float* __restrict__ a, unsigned short* __restrict__ abf,
    unsigned short* __restrict__ a_last)
{
  int r = blockIdx.x;                 // 0..8447
  int bb = r / LTOT, t = r - bb*LTOT;
  const float* row = (t < 2048) ? (x + ((size_t)bb*2048 + t)*DM)
                                : (toks + (size_t)(t - 2048)*DM);
  int tid = threadIdx.x;
  float v0 = row[tid], v1 = row[tid + 256];
  float s = v0 + v1, sq = v0*v0 + v1*v1;
  #pragma unroll
  for (int o = 32; o > 0; o >>= 1){ s += __shfl_down(s,o); sq += __shfl_down(sq,o); }
  __shared__ float sb[8];
  if ((tid & 63) == 0){ sb[tid>>6] = s; sb[4 + (tid>>6)] = sq; }
  __syncthreads();
  float S  = sb[0]+sb[1]+sb[2]+sb[3];
  float SQ = sb[4]+sb[5]+sb[6]+sb[7];
  float mean = S * (1.f/DM);
  float var  = SQ * (1.f/DM) - mean*mean;
  float rs = rsqrtf(var + 1e-5f);
  size_t o0 = (size_t)r*DM;
  float r0 = (v0 - mean)*rs*g1[tid]       + b1[tid];
  float r1 = (v1 - mean)*rs*g1[tid + 256] + b1[tid + 256];
  a[o0 + tid]       = r0;
  a[o0 + tid + 256] = r1;
  unsigned short h0 = f2bf(r0), h1 = f2bf(r1);
  abf[o0 + tid]       = h0;
  abf[o0 + tid + 256] = h1;
  if (t >= 2048) {
    size_t lr = (size_t)(bb*64 + (t - 2048))*DM;
    a_last[lr + tid]       = h0;
    a_last[lr + tid + 256] = h1;
  }
}

// ---------------- fp32 -> bf16 bulk convert (4 elems/thread) ----------------
__global__ __launch_bounds__(256) void f32_to_bf16_kernel(
    const float* __restrict__ in, unsigned short* __restrict__ out, int n4)
{
  int i = blockIdx.x*256 + threadIdx.x;
  if (i >= n4) return;
  float4 v = reinterpret_cast<const float4*>(in)[i];
  ushort4 o;
  o.x = f2bf(v.x); o.y = f2bf(v.y); o.z = f2bf(v.z); o.w = f2bf(v.w);
  reinterpret_cast<ushort4*>(out)[i] = o;
}

// ---------------- bf16 MFMA GEMM: C[M,N](fp32) = A[M,K] * W[N,K]^T ----------------
// BM=128, BN=64, BK=32, 256 threads (4 waves in 2x2), 16x16x32 MFMA, 4x2 frags/wave.
__global__ __launch_bounds__(256) void gemm_bf16(
    const unsigned short* __restrict__ A, const unsigned short* __restrict__ W,
    float* __restrict__ C, int M, int N, int K, int ldc)
{
  __shared__ unsigned short As[128][40];   // stride 80B: 16B-aligned, 2-way banks (free)
  __shared__ unsigned short Bs[64][40];
  int tid  = threadIdx.x;
  int lane = tid & 63, wid = tid >> 6;
  int wm = wid >> 1, wn = wid & 1;         // 2x2 wave grid
  int l15 = lane & 15, l4 = lane >> 4;
  int m0 = blockIdx.x * 128, n0 = blockIdx.y * 64;
  int sr = tid >> 2, sc = (tid & 3) * 8;   // staging: row, col(elem)

  f32x4 acc[4][2];
  #pragma unroll
  for (int i = 0; i < 4; ++i)
    #pragma unroll
    for (int j = 0; j < 2; ++j) acc[i][j] = (f32x4)0.f;

  for (int k0 = 0; k0 < K; k0 += 32) {
    #pragma unroll
    for (int rr = 0; rr < 2; ++rr) {
      int r = sr + rr*64;
      uint4 v = *reinterpret_cast<const uint4*>(A + (size_t)(m0 + r)*K + k0 + sc);
      *reinterpret_cast<uint4*>(&As[r][sc]) = v;
    }
    {
      int col = n0 + sr;
      uint4 v = make_uint4(0u,0u,0u,0u);
      if (col < N) v = *reinterpret_cast<const uint4*>(W + (size_t)col*K + k0 + sc);
      *reinterpret_cast<uint4*>(&Bs[sr][sc]) = v;
    }
    __syncthreads();
    short8 bfrag[2];
    #pragma unroll
    for (int fn = 0; fn < 2; ++fn)
      bfrag[fn] = *reinterpret_cast<const short8*>(&Bs[wn*32 + fn*16 + l15][l4*8]);
    #pragma unroll
    for (int fm = 0; fm < 4; ++fm) {
      short8 afrag = *reinterpret_cast<const short8*>(&As[wm*64 + fm*16 + l15][l4*8]);
      acc[fm][0] = __builtin_amdgcn_mfma_f32_16x16x32_bf16(afrag, bfrag[0], acc[fm][0], 0, 0, 0);
      acc[fm][1] = __builtin_amdgcn_mfma_f32_16x16x32_bf16(afrag, bfrag[1], acc[fm][1], 0, 0, 0);
    }
    __syncthreads();
  }
  #pragma unroll
  for (int fm = 0; fm < 4; ++fm)
    #pragma unroll
    for (int fn = 0; fn < 2; ++fn) {
      int col = n0 + wn*32 + fn*16 + l15;
      if (col < N)
        #pragma unroll
        for (int j = 0; j < 4; ++j) {
          int row = m0 + wm*64 + fm*16 + l4*4 + j;
          C[(size_t)row*ldc + col] = acc[fm][fn][j];
        }
    }
}

// ---------------- causal depthwise conv (K=4) + silu; fp32 u, bf16 u, compact last rows ----------------
__global__ __launch_bounds__(256) void conv_silu_kernel(
    const float* __restrict__ upre, const float* __restrict__ Wc,
    const float* __restrict__ bc, float* __restrict__ u,
    unsigned short* __restrict__ ubf, unsigned short* __restrict__ u_last)
{
  size_t idx = (size_t)blockIdx.x*256 + threadIdx.x;   // < 8448*1024
  int d = (int)(idx & 1023);
  int r = (int)(idx >> 10);
  int t = r % LTOT;
  float4 w4 = *reinterpret_cast<const float4*>(Wc + (size_t)d*4);
  float acc = bc[d];
  const float* up = upre + idx;
  if (t >= 3) acc = fmaf(up[-3*DIN], w4.x, acc);
  if (t >= 2) acc = fmaf(up[-2*DIN], w4.y, acc);
  if (t >= 1) acc = fmaf(up[-1*DIN], w4.z, acc);
  acc = fmaf(up[0], w4.w, acc);
  float res = fast_silu(acc);
  u[idx] = res;
  unsigned short hb = f2bf(res);
  ubf[idx] = hb;
  if (t >= 2048) {
    int bb = r / LTOT;
    u_last[(size_t)(bb*64 + (t - 2048))*DIN + d] = hb;
  }
}

// ---------------- delta = softplus(dt @ W_dt^T + b_dt); write delta & delta*u TRANSPOSED ----------------
__global__ __launch_bounds__(256) void delta_kernel(
    const float* __restrict__ dbl, const float* __restrict__ W_dt,
    const float* __restrict__ b_dt, const float* __restrict__ u,
    float* __restrict__ deltaT, float* __restrict__ duT)
{
  __shared__ float dts[32][33];
  __shared__ float wds[32][33];
  __shared__ float dT[32][33];
  __shared__ float uT[32][33];
  int r0 = blockIdx.x * 32;
  int d0 = blockIdx.y * 32;
  int bb = r0 / LTOT, t0 = r0 % LTOT;   // 2112 % 32 == 0 -> no batch straddling
  int tid = threadIdx.x;
  #pragma unroll
  for (int p = 0; p < 4; ++p) {
    int o = tid + p*256;
    int rl = o >> 5, j = o & 31;
    dts[rl][j] = dbl[(size_t)(r0 + rl)*288 + j];
    wds[rl][j] = W_dt[(size_t)(d0 + rl)*32 + j];
  }
  __syncthreads();
  #pragma unroll
  for (int p = 0; p < 4; ++p) {
    int o = tid + p*256;
    int dl = o & 31, rl = o >> 5;
    float acc = b_dt[d0 + dl];
    #pragma unroll
    for (int j = 0; j < 32; ++j) acc = fmaf(dts[rl][j], wds[dl][j], acc);
    float delta = (acc > 20.f) ? acc : __logf(1.f + __expf(acc));
    float uu = u[(size_t)(r0 + rl)*DIN + d0 + dl];
    dT[dl][rl] = delta;
    uT[dl][rl] = delta * uu;
  }
  __syncthreads();
  #pragma unroll
  for (int p = 0; p < 4; ++p) {
    int o = tid + p*256;
    int dl = o >> 5, ti = o & 31;
    size_t gi = ((size_t)bb*DIN + d0 + dl)*LTOT + t0 + ti;
    deltaT[gi] = dT[dl][ti];
    duT[gi]    = uT[dl][ti];
  }
}

// ---------------- selective scan v3: DG=2, 2048 blocks, uniform scalar d/u loads ----------------
__global__ __launch_bounds__(256) void scan_kernel(
    const float* __restrict__ deltaT, const float* __restrict__ duT,
    const float* __restrict__ dbl, const float* __restrict__ Cm,
    const float* __restrict__ A_log, float* __restrict__ y)
{
  int blk = blockIdx.x;          // 0..2047
  int bb = blk >> 9;
  int d0 = (blk & 511) << 1;
  int n = threadIdx.x;
  float Ak[2], h[2] = {0.f, 0.f};
  #pragma unroll
  for (int g = 0; g < 2; ++g) {
    float al = A_log[(size_t)(d0+g)*NST + n];
    Ak[g] = -__builtin_amdgcn_exp2f(al * 1.44269504089f) * 1.44269504089f;
  }
  const size_t basebd = ((size_t)bb*DIN + d0)*LTOT;
  const float* __restrict__ pd = deltaT + basebd;   // uniform base
  const float* __restrict__ pu = duT    + basebd;
  const float* __restrict__ Bp = dbl + (size_t)bb*LTOT*288 + 32 + n;

  // ---- fast phase: t in [0, 2048), 4 timesteps per iteration ----
  for (int t0c = 0; t0c < 2048; t0c += 4) {
    float Bnv[4];
    #pragma unroll
    for (int i = 0; i < 4; ++i) Bnv[i] = Bp[(size_t)(t0c + i)*288];
    float dv[2][4], uv[2][4];
    #pragma unroll
    for (int g = 0; g < 2; ++g) {
      float4 dq = *reinterpret_cast<const float4*>(pd + (size_t)g*LTOT + t0c);
      float4 uq = *reinterpret_cast<const float4*>(pu + (size_t)g*LTOT + t0c);
      dv[g][0]=dq.x; dv[g][1]=dq.y; dv[g][2]=dq.z; dv[g][3]=dq.w;
      uv[g][0]=uq.x; uv[g][1]=uq.y; uv[g][2]=uq.z; uv[g][3]=uq.w;
    }
    #pragma unroll
    for (int i = 0; i < 4; ++i) {
      float Bn = Bnv[i];
      #pragma unroll
      for (int g = 0; g < 2; ++g) {
        float dA = __builtin_amdgcn_exp2f(dv[g][i] * Ak[g]);
        h[g] = fmaf(dA, h[g], uv[g][i] * Bn);
      }
    }
  }

  // ---- readout phase: last 64 timesteps, also y = h . C ----
  __shared__ float red[4][2];
  for (int t = 2048; t < 2112; ++t) {
    float Bn = Bp[(size_t)t*288];
    #pragma unroll
    for (int g = 0; g < 2; ++g) {
      float dA = __builtin_amdgcn_exp2f(pd[(size_t)g*LTOT + t] * Ak[g]);
      h[g] = fmaf(dA, h[g], pu[(size_t)g*LTOT + t] * Bn);
    }
    float Cn = Cm[((size_t)(bb*64 + (t - 2048)))*NST + n];
    #pragma unroll
    for (int g = 0; g < 2; ++g) {
      float v = h[g] * Cn;
      #pragma unroll
      for (int o = 32; o > 0; o >>= 1) v += __shfl_down(v, o);
      if ((threadIdx.x & 63) == 0) red[threadIdx.x >> 6][g] = v;
    }
    __syncthreads();
    if (threadIdx.x < 2) {
      float sv = red[0][threadIdx.x] + red[1][threadIdx.x]
               + red[2][threadIdx.x] + red[3][threadIdx.x];
      y[((size_t)(bb*64 + (t - 2048)))*DIN + d0 + threadIdx.x] = sv;
    }
    __syncthreads();
  }
}

// ---------------- y2 = (y_scan + u*Dp) * silu(z_raw) ----------------
__global__ __launch_bounds__(256) void y2_kernel(
    const float* __restrict__ y, const float* __restrict__ u, const float* __restrict__ zs,
    const float* __restrict__ Dp, float* __restrict__ y2)
{
  int idx = blockIdx.x*256 + threadIdx.x;  // < 262144
  int rr = idx >> 10, d = idx & 1023;
  int bb = rr >> 6, tt = rr & 63;
  size_t r = (size_t)bb*LTOT + 2048 + tt;
  float yv = y[idx] + u[r*DIN + d] * Dp[d];
  y2[idx] = yv * fast_silu(zs[idx]);
}

// ---------------- out_proj + residual (residual row = fused token) ----------------
__global__ __launch_bounds__(256) void outproj_kernel(
    const float* __restrict__ y2, const float* __restrict__ Wout,
    const float* __restrict__ toks, float* __restrict__ hfin)
{
  __shared__ float ys[4][DIN];
  int rb = blockIdx.x;                 // 64 blocks, 4 rows each
  int tid = threadIdx.x;
  #pragma unroll
  for (int rr = 0; rr < 4; ++rr)
    #pragma unroll
    for (int j = 0; j < 4; ++j)
      ys[rr][tid + j*256] = y2[(size_t)(rb*4 + rr)*DIN + tid + j*256];
  __syncthreads();
  #pragma unroll
  for (int cj = 0; cj < 2; ++cj) {
    int cidx = tid + cj*256;
    const float* wr = Wout + (size_t)cidx*DIN;
    float a0=0.f,a1=0.f,a2=0.f,a3=0.f;
    for (int k = 0; k < DIN; k += 4) {
      float4 w4 = *reinterpret_cast<const float4*>(wr + k);
      float4 r0 = *reinterpret_cast<const float4*>(&ys[0][k]);
      float4 r1 = *reinterpret_cast<const float4*>(&ys[1][k]);
      float4 r2 = *reinterpret_cast<const float4*>(&ys[2][k]);
      float4 r3 = *reinterpret_cast<const float4*>(&ys[3][k]);
      a0=fmaf(r0.x,w4.x,a0); a0=fmaf(r0.y,w4.y,a0); a0=fmaf(r0.z,w4.z,a0); a0=fmaf(r0.w,w4.w,a0);
      a1=fmaf(r1.x,w4.x,a1); a1=fmaf(r1.y,w4.y,a1); a1=fmaf(r1.z,w4.z,a1); a1=fmaf(r1.w,w4.w,a1);
      a2=fmaf(r2.x,w4.x,a2); a2=fmaf(r2.y,w4.y,a2); a2=fmaf(r2.z,w4.z,a2); a2=fmaf(r2.w,w4.w,a2);
      a3=fmaf(r3.x,w4.x,a3); a3=fmaf(r3.y,w4.y,a3); a3=fmaf(r3.z,w4.z,a3); a3=fmaf(r3.w,w4.w,a3);
    }
    float accs[4] = {a0,a1,a2,a3};
    #pragma unroll
    for (int rr = 0; rr < 4; ++rr) {
      int rg = rb*4 + rr;
      hfin[(size_t)rg*DM + cidx] = accs[rr] + toks[(size_t)(rg & 63)*DM + cidx];
    }
  }
}

// ---------------- LN2 + head GEMM + residual ----------------
__global__ __launch_bounds__(256) void head_kernel(
    const float* __restrict__ hfin, const float* __restrict__ g2, const float* __restrict__ b2,
    const float* __restrict__ Wh, const float* __restrict__ bh, float* __restrict__ out)
{
  int rr = blockIdx.x;                 // 0..255
  int tid = threadIdx.x;
  float v0 = hfin[(size_t)rr*DM + tid];
  float v1 = hfin[(size_t)rr*DM + tid + 256];
  float s = v0 + v1, sq = v0*v0 + v1*v1;
  #pragma unroll
  for (int o = 32; o > 0; o >>= 1){ s += __shfl_down(s,o); sq += __shfl_down(sq,o); }
  __shared__ float sb[8];
  if ((tid & 63) == 0){ sb[tid>>6] = s; sb[4 + (tid>>6)] = sq; }
  __syncthreads();
  float S  = sb[0]+sb[1]+sb[2]+sb[3];
  float SQ = sb[4]+sb[5]+sb[6]+sb[7];
  float mean = S * (1.f/DM);
  float rs = rsqrtf(SQ * (1.f/DM) - mean*mean + 1e-5f);
  __shared__ float as[DM];
  as[tid]       = (v0 - mean)*rs*g2[tid]       + b2[tid];
  as[tid + 256] = (v1 - mean)*rs*g2[tid + 256] + b2[tid + 256];
  __syncthreads();
  #pragma unroll
  for (int cj = 0; cj < 2; ++cj) {
    int cidx = tid + cj*256;
    const float* wr = Wh + (size_t)cidx*DM;
    float acc = bh[cidx] + (cj ? v1 : v0);
    for (int k = 0; k < DM; k += 4) {
      float4 w4 = *reinterpret_cast<const float4*>(wr + k);
      float4 a4 = *reinterpret_cast<const float4*>(&as[k]);
      acc = fmaf(a4.x,w4.x,acc); acc = fmaf(a4.y,w4.y,acc);
      acc = fmaf(a4.z,w4.z,acc); acc = fmaf(a4.w,w4.w,acc);
    }
    out[(size_t)rr*DM + cidx] = acc;
  }
}

extern "C" void kernel_launch(void* const* d_in, const int* in_sizes, int n_in,
                              void* d_out, int out_size, void* d_ws, size_t ws_size,
                              hipStream_t stream) {
  const float* x      = (const float*)d_in[0];
  const float* toks   = (const float*)d_in[1];
  const float* g1     = (const float*)d_in[2];
  const float* b1     = (const float*)d_in[3];
  const float* g2     = (const float*)d_in[4];
  const float* b2     = (const float*)d_in[5];
  const float* W_head = (const float*)d_in[6];
  const float* b_head = (const float*)d_in[7];
  const float* W_in   = (const float*)d_in[8];
  const float* W_conv = (const float*)d_in[9];
  const float* b_conv = (const float*)d_in[10];
  const float* W_xp   = (const float*)d_in[11];
  const float* W_dt   = (const float*)d_in[12];
  const float* b_dt   = (const float*)d_in[13];
  const float* A_log  = (const float*)d_in[14];
  const float* Dp     = (const float*)d_in[15];
  const float* W_out  = (const float*)d_in[16];

  float* ws = (float*)d_ws;
  float* a_buf   = ws;                                  // 8448*512
  float* u_pre   = a_buf   + (size_t)NROWS*DM;          // 8448*1024 (reused as deltaT)
  float* u_buf   = u_pre   + (size_t)NROWS*DIN;         // 8448*1024
  float* dbl_buf = u_buf   + (size_t)NROWS*DIN;         // 8448*288
  float* duT     = dbl_buf + (size_t)NROWS*288;         // 8448*1024
  float* zs      = duT     + (size_t)NROWS*DIN;         // 256*1024 (raw, silu in y2)
  float* Cm      = zs      + (size_t)256*DIN;           // 256*256
  float* y_buf   = Cm      + (size_t)256*NST;           // 256*1024
  float* y2_buf  = y_buf   + (size_t)256*DIN;           // 256*1024
  float* hfin    = y2_buf  + (size_t)256*DIN;           // 256*512
  float* tail    = hfin    + (size_t)256*DM;
  float* deltaT  = u_pre;                               // overlay (u_pre dead after conv)

  // compact last-64-row bf16 buffers (after hfin)
  unsigned short* a_last_bf16 = (unsigned short*)tail;              // 256*512
  unsigned short* u_last_bf16 = a_last_bf16 + (size_t)256*DM;       // 256*1024

  // bf16 staging buffers overlay duT (dead until delta_kernel runs):
  // a_bf16 8.65MB + u_bf16 17.3MB + wi(full 2048x512) 2.1MB + wx(full 544x1024) 1.1MB
  //   = 29.2MB < duT's 34.6MB.
  unsigned short* a_bf16  = (unsigned short*)duT;
  unsigned short* u_bf16  = a_bf16 + (size_t)NROWS*DM;
  unsigned short* wi_bf16 = u_bf16 + (size_t)NROWS*DIN;
  unsigned short* wx_bf16 = wi_bf16 + (size_t)2*DIN*DM;

  f32_to_bf16_kernel<<<(2*DIN*DM/4 + 255)/256, 256, 0, stream>>>(W_in, wi_bf16, 2*DIN*DM/4);
  f32_to_bf16_kernel<<<(544*DIN/4 + 255)/256, 256, 0, stream>>>(W_xp, wx_bf16, 544*DIN/4);

  ln1_kernel<<<NROWS, 256, 0, stream>>>(x, toks, g1, b1, a_buf, a_bf16, a_last_bf16);
  // in_proj u-half (all rows)
  gemm_bf16<<<dim3(NROWS/128, DIN/64), 256, 0, stream>>>(a_bf16, wi_bf16, u_pre,
                                                         NROWS, DIN, DM, DIN);
  // z (last 64 rows only): zs = a_last @ Wz^T
  gemm_bf16<<<dim3(2, DIN/64), 256, 0, stream>>>(a_last_bf16, wi_bf16 + (size_t)DIN*DM,
                                                 zs, 256, DIN, DM, DIN);
  conv_silu_kernel<<<(NROWS*DIN)/256, 256, 0, stream>>>(u_pre, W_conv, b_conv,
                                                        u_buf, u_bf16, u_last_bf16);
  // x_proj dt+B (all rows)
  gemm_bf16<<<dim3(NROWS/128, (288 + 63)/64), 256, 0, stream>>>(u_bf16, wx_bf16, dbl_buf,
                                                                NROWS, 288, DIN, 288);
  // C (last 64 rows only): Cm = u_last @ WxpC^T
  gemm_bf16<<<dim3(2, NST/64), 256, 0, stream>>>(u_last_bf16, wx_bf16 + (size_t)288*DIN,
                                                 Cm, 256, NST, DIN, NST);
  delta_kernel<<<dim3(NROWS/32, DIN/32), 256, 0, stream>>>(dbl_buf, W_dt, b_dt, u_buf,
                                                           deltaT, duT);
  scan_kernel<<<2048, 256, 0, stream>>>(deltaT, duT, dbl_buf, Cm, A_log, y_buf);
  y2_kernel<<<1024, 256, 0, stream>>>(y_buf, u_buf, zs, Dp, y2_buf);
  outproj_kernel<<<64, 256, 0, stream>>>(y2_buf, W_out, toks, hfin);
  head_kernel<<<256, 256, 0, stream>>>(hfin, g2, b2, W_head, b_head, (float*)d_out);
}